// Round 6
// baseline (711.791 us; speedup 1.0000x reference)
//
#include <hip/hip_runtime.h>

// ---------- types / helpers ----------
typedef short bf16x8 __attribute__((ext_vector_type(8)));
typedef float f32x4 __attribute__((ext_vector_type(4)));

__device__ __forceinline__ float b2f(unsigned short u) {
  unsigned x = ((unsigned)u) << 16;
  float f;
  __builtin_memcpy(&f, &x, 4);
  return f;
}
__device__ __forceinline__ unsigned short f2b(float f) {
  unsigned x;
  __builtin_memcpy(&x, &f, 4);
  unsigned r = (x + 0x7FFFu + ((x >> 16) & 1u)) >> 16;  // RNE
  return (unsigned short)r;
}
__device__ __forceinline__ float definan(float f) {
  unsigned b;
  __builtin_memcpy(&b, &f, 4);
  if ((b & 0x7F800000u) == 0x7F800000u) return 0.f;
  return f;
}
__device__ __forceinline__ f32x4 mfma16(bf16x8 a, bf16x8 b, f32x4 c) {
  return __builtin_amdgcn_mfma_f32_16x16x32_bf16(a, b, c, 0, 0, 0);
}

#define GLL(g, l) __builtin_amdgcn_global_load_lds( \
    (const __attribute__((address_space(1))) void*)(g), \
    (__attribute__((address_space(3))) void*)(l), 16, 0, 0)

// ---------- input conversion: fp32 inputs -> bf16 arena ----------
// arena element offsets (all 8-aligned):
//   x : [0, 16588800)   xp: [.., 16957440)   qw: [.., 17743872)
//   qb: [.., 17745408)  pw: [.., 18007552)   pb: [.., 18008064)
__global__ __launch_bounds__(256)
void convert_inputs(const float* __restrict__ x, const float* __restrict__ xp,
                    const float* __restrict__ qw, const float* __restrict__ qb,
                    const float* __restrict__ pw, const float* __restrict__ pb,
                    unsigned short* __restrict__ arena) {
  long g = ((long)blockIdx.x * 256 + threadIdx.x) * 8;  // 8793*256*8 == 18008064 exactly
  const float* src;
  long off;
  if (g < 16588800L)      { src = x;  off = g; }
  else if (g < 16957440L) { src = xp; off = g - 16588800L; }
  else if (g < 17743872L) { src = qw; off = g - 16957440L; }
  else if (g < 17745408L) { src = qb; off = g - 17743872L; }
  else if (g < 18007552L) { src = pw; off = g - 17745408L; }
  else                    { src = pb; off = g - 18007552L; }
  float4 a = *(const float4*)(src + off);
  float4 b = *(const float4*)(src + off + 4);
  unsigned short o[8] = {f2b(a.x), f2b(a.y), f2b(a.z), f2b(a.w),
                         f2b(b.x), f2b(b.y), f2b(b.z), f2b(b.w)};
  uint4 pack;
  __builtin_memcpy(&pack, o, 16);
  *(uint4*)(arena + g) = pack;
}

// ---------- GEMM: C = A (MxK, row-major, bf16) * B^T (NxK, bf16) + bias ----------
// wf32: epilogue writes float (final projection) vs bf16 (intermediate).
__global__ __launch_bounds__(256, 2)
void gemm_bt(const unsigned short* __restrict__ A, const unsigned short* __restrict__ B,
             const unsigned short* __restrict__ bias, void* __restrict__ Co,
             int M, int K, int lda, int ldb, int ldc, int wf32) {
  __shared__ unsigned short Al[4096];
  __shared__ unsigned short Bl[4096];
  const int tid = threadIdx.x;
  const int bm = blockIdx.x, bn = blockIdx.y;
  const int lane = tid & 63;
  const int wid = tid >> 6;
  const int wm = (wid >> 1) * 64, wn = (wid & 1) * 64;
  const int mrow = lane & 15, kgrp = (lane >> 4) * 8;

  f32x4 acc[4][4] = {};

  const int c0 = tid, c1 = tid + 256;
  const int r0 = c0 >> 2, o0 = (c0 & 3) * 8;
  const int r1 = c1 >> 2, o1 = (c1 & 3) * 8;
  int am0 = bm * 128 + r0; if (am0 > M - 1) am0 = M - 1;
  int am1 = bm * 128 + r1; if (am1 > M - 1) am1 = M - 1;
  const unsigned short* ap0 = A + (size_t)am0 * lda + o0;
  const unsigned short* ap1 = A + (size_t)am1 * lda + o1;
  const unsigned short* bp0 = B + (size_t)(bn * 128 + r0) * ldb + o0;
  const unsigned short* bp1 = B + (size_t)(bn * 128 + r1) * ldb + o1;

  const int nkt = K >> 5;
  for (int kt = 0; kt < nkt; kt++) {
    GLL(ap0, &Al[c0 * 8]);
    GLL(ap1, &Al[c1 * 8]);
    GLL(bp0, &Bl[c0 * 8]);
    GLL(bp1, &Bl[c1 * 8]);
    ap0 += 32; ap1 += 32; bp0 += 32; bp1 += 32;
    __syncthreads();
    bf16x8 af[4], bfr[4];
#pragma unroll
    for (int mi = 0; mi < 4; mi++)
      af[mi] = *(const bf16x8*)&Al[(wm + mi * 16 + mrow) * 32 + kgrp];
#pragma unroll
    for (int ni = 0; ni < 4; ni++)
      bfr[ni] = *(const bf16x8*)&Bl[(wn + ni * 16 + mrow) * 32 + kgrp];
#pragma unroll
    for (int mi = 0; mi < 4; mi++)
#pragma unroll
      for (int ni = 0; ni < 4; ni++)
        acc[mi][ni] = mfma16(af[mi], bfr[ni], acc[mi][ni]);
    __syncthreads();
  }

#pragma unroll
  for (int ni = 0; ni < 4; ni++) {
    const int gcol = bn * 128 + wn + ni * 16 + mrow;
    const float bv = b2f(bias[gcol]);
#pragma unroll
    for (int mi = 0; mi < 4; mi++) {
      f32x4 v = acc[mi][ni];
#pragma unroll
      for (int r = 0; r < 4; r++) {
        int grow = bm * 128 + wm + mi * 16 + (lane >> 4) * 4 + r;
        if (grow < M) {
          float val = definan(v[r] + bv);
          if (wf32) ((float*)Co)[(size_t)grow * ldc + gcol] = val;
          else      ((unsigned short*)Co)[(size_t)grow * ldc + gcol] = f2b(val);
        }
      }
    }
  }
}

// ---------- pooled QKV: 720 tokens, only k/v, into padded (5,16,20,512) ----------
__global__ __launch_bounds__(256)
void pooled_qkv(const unsigned short* __restrict__ xp, const unsigned short* __restrict__ qw,
                const unsigned short* __restrict__ qb, unsigned short* __restrict__ kp,
                unsigned short* __restrict__ vp) {
  int gid = blockIdx.x * 256 + threadIdx.x;
  if (gid >= 720 * 1024) return;
  int n = gid & 1023, m = gid >> 10;
  int t = m / 144, rem = m - t * 144;
  int ph = rem / 12, pww = rem - ph * 12;
  const unsigned short* a = xp + (size_t)((ph * 12 + pww) * 5 + t) * 512;
  const unsigned short* b = qw + (size_t)(512 + n) * 512;
  float acc = b2f(qb[512 + n]);
#pragma unroll 4
  for (int k = 0; k < 512; k += 8) {
    uint4 av = *(const uint4*)(a + k);
    uint4 bv = *(const uint4*)(b + k);
    const unsigned short* ae = (const unsigned short*)&av;
    const unsigned short* be = (const unsigned short*)&bv;
#pragma unroll
    for (int i = 0; i < 8; i++) acc += b2f(ae[i]) * b2f(be[i]);
  }
  size_t off = ((size_t)(t * 16 + ph + 2) * 20 + (pww + 4)) * 512;
  if (n < 512) kp[off + n] = f2b(definan(acc));
  else         vp[off + n - 512] = f2b(definan(acc));
}

// ---------- fused window attention: one block per (window, head) ----------
__global__ __launch_bounds__(512, 2)
void attn_win(const unsigned short* __restrict__ qkv, const unsigned short* __restrict__ kp,
              const unsigned short* __restrict__ vp, unsigned short* __restrict__ op) {
  const int win = blockIdx.x, head = blockIdx.y;
  const int wh = win / 12, ww = win - wh * 12;
  const int tid = threadIdx.x;
  const int lane = tid & 63, wv = tid >> 6;
  const int mrow = lane & 15, kgrp = (lane >> 4) * 8;

  __shared__ unsigned short Klds[32 * 136];
  __shared__ unsigned short VT[128 * 40];
  __shared__ unsigned short Plds[8 * 32 * 40];
  __shared__ float Bias[1056];

  for (int i = tid; i < 1056; i += 512) {
    float b = 0.f;
    if (i >= 1050) b = -100000.f;
    else if (i >= 825) {
      int pidx = i - 825;
      int rem = pidx % 45;
      int fi = rem / 9, fj = rem - fi * 9;
      int ph = wh + fi - 2, pw2 = ww + fj - 4;
      if (ph < 0 || ph >= 12 || pw2 < 0 || pw2 >= 12) b = -144.269504089f;  // -100*log2(e)
    }
    Bias[i] = b;
  }

  bf16x8 qf[2][4];
#pragma unroll
  for (int mi = 0; mi < 2; mi++) {
    int wrow = wv * 32 + mi * 16 + mrow;
    if (wrow < 225) {
      int t = wrow / 45, rem = wrow - t * 45;
      int ii = rem / 9, jj = rem - ii * 9;
      int g = (t * 60 + wh * 5 + ii) * 108 + ww * 9 + jj;
      const unsigned short* qp = qkv + (size_t)g * 1536 + head * 128;
#pragma unroll
      for (int ks = 0; ks < 4; ks++)
        qf[mi][ks] = *(const bf16x8*)(qp + ks * 32 + kgrp);
    } else {
      bf16x8 z = {0, 0, 0, 0, 0, 0, 0, 0};
#pragma unroll
      for (int ks = 0; ks < 4; ks++) qf[mi][ks] = z;
    }
  }

  f32x4 oacc[2][8] = {};
  f32x4 lacc[2] = {};
  bf16x8 ones;
  { short o1 = (short)0x3F80; ones = (bf16x8){o1, o1, o1, o1, o1, o1, o1, o1}; }

  const float c1 = 0.12752713f;  // log2(e)/sqrt(128)

  const int tt = tid & 255;
  const int srow = tt >> 3, sch = tt & 7;
  const bool isV = tid >= 256;

  __syncthreads();

  for (int tile = 0; tile < 33; tile++) {
    const int widx = tile * 32 + srow;
    const unsigned short* ksrc = nullptr;
    const unsigned short* vsrc = nullptr;
    if (widx < 225) {
      int t = widx / 45, rem = widx - t * 45;
      int ii = rem / 9, jj = rem - ii * 9;
      int g = (t * 60 + wh * 5 + ii) * 108 + ww * 9 + jj;
      ksrc = qkv + (size_t)g * 1536 + 512 + head * 128;
      vsrc = ksrc + 512;
    } else if (widx < 825) {
      int rr = widx - 225;
      int t = rr / 120, v = rr - t * 120;
      int p = v / 30, q = v - p * 30;
      int ii, jj;
      if (p == 0) {
        if (q < 12) { ii = q >> 2; jj = 5 + (q & 3); }
        else { int q2 = q - 12; int d9 = q2 / 9; ii = 3 + d9; jj = q2 - d9 * 9; }
      } else if (p == 1) {
        if (q < 12) { ii = q >> 2; jj = q & 3; }
        else { int q2 = q - 12; int d9 = q2 / 9; ii = 3 + d9; jj = q2 - d9 * 9; }
      } else if (p == 2) {
        if (q < 18) { int d9 = q / 9; ii = d9; jj = q - d9 * 9; }
        else { int q2 = q - 18; ii = 2 + (q2 >> 2); jj = 5 + (q2 & 3); }
      } else {
        if (q < 18) { int d9 = q / 9; ii = d9; jj = q - d9 * 9; }
        else { int q2 = q - 18; ii = 2 + (q2 >> 2); jj = q2 & 3; }
      }
      int gh = wh * 5 + ii + ((p < 2) ? 2 : -2);
      if (gh >= 60) gh -= 60; if (gh < 0) gh += 60;
      int gw = ww * 9 + jj + (((p & 1) == 0) ? 4 : -4);
      if (gw >= 108) gw -= 108; if (gw < 0) gw += 108;
      int g = (t * 60 + gh) * 108 + gw;
      ksrc = qkv + (size_t)g * 1536 + 512 + head * 128;
      vsrc = ksrc + 512;
    } else if (widx < 1050) {
      int pidx = widx - 825;
      int t = pidx / 45, rem = pidx - t * 45;
      int fi = rem / 9, fj = rem - fi * 9;
      size_t off = ((size_t)(t * 16 + wh + fi) * 20 + (ww + fj)) * 512 + head * 128;
      ksrc = kp + off;
      vsrc = vp + off;
    }

    uint4 z4; z4.x = z4.y = z4.z = z4.w = 0u;
    if (!isV) {
      uint4 d0 = ksrc ? *(const uint4*)(ksrc + sch * 16) : z4;
      uint4 d1 = ksrc ? *(const uint4*)(ksrc + sch * 16 + 8) : z4;
      *(uint4*)&Klds[srow * 136 + sch * 16] = d0;
      *(uint4*)&Klds[srow * 136 + sch * 16 + 8] = d1;
    } else {
      uint4 d0 = vsrc ? *(const uint4*)(vsrc + sch * 16) : z4;
      uint4 d1 = vsrc ? *(const uint4*)(vsrc + sch * 16 + 8) : z4;
      unsigned short e[16];
      __builtin_memcpy(e, &d0, 16);
      __builtin_memcpy(e + 8, &d1, 16);
#pragma unroll
      for (int q8 = 0; q8 < 16; q8++)
        VT[(sch * 16 + q8) * 40 + srow] = e[q8];
    }
    __syncthreads();

    f32x4 sacc[2][2] = {};
#pragma unroll
    for (int ks = 0; ks < 4; ks++) {
#pragma unroll
      for (int ni = 0; ni < 2; ni++) {
        bf16x8 kf = *(const bf16x8*)&Klds[(ni * 16 + mrow) * 136 + ks * 32 + kgrp];
        sacc[0][ni] = mfma16(qf[0][ks], kf, sacc[0][ni]);
        sacc[1][ni] = mfma16(qf[1][ks], kf, sacc[1][ni]);
      }
    }

    const float b0 = Bias[tile * 32 + mrow];
    const float b1 = Bias[tile * 32 + 16 + mrow];
#pragma unroll
    for (int mi = 0; mi < 2; mi++) {
#pragma unroll
      for (int ni = 0; ni < 2; ni++) {
        const float bb = ni ? b1 : b0;
        f32x4 s = sacc[mi][ni];
#pragma unroll
        for (int r = 0; r < 4; r++) {
          float e = definan(s[r]) * c1 + bb;
          e = fminf(e, 80.f);
          float pe = __builtin_exp2f(e);
          int prow = mi * 16 + (lane >> 4) * 4 + r;
          Plds[(wv * 32 + prow) * 40 + ni * 16 + mrow] = f2b(pe);
        }
      }
    }
    __syncthreads();

    bf16x8 pf0 = *(const bf16x8*)&Plds[(wv * 32 + mrow) * 40 + kgrp];
    bf16x8 pf1 = *(const bf16x8*)&Plds[(wv * 32 + 16 + mrow) * 40 + kgrp];
    lacc[0] = mfma16(pf0, ones, lacc[0]);
    lacc[1] = mfma16(pf1, ones, lacc[1]);
#pragma unroll
    for (int nt = 0; nt < 8; nt++) {
      bf16x8 vf = *(const bf16x8*)&VT[(nt * 16 + mrow) * 40 + kgrp];
      oacc[0][nt] = mfma16(pf0, vf, oacc[0][nt]);
      oacc[1][nt] = mfma16(pf1, vf, oacc[1][nt]);
    }
    __syncthreads();
  }

  const size_t obase = (size_t)win * 225;
#pragma unroll
  for (int mi = 0; mi < 2; mi++) {
    f32x4 lv = lacc[mi];
    f32x4 ri;
#pragma unroll
    for (int r = 0; r < 4; r++) ri[r] = 1.0f / fmaxf(lv[r], 1e-30f);
#pragma unroll
    for (int nt = 0; nt < 8; nt++) {
      f32x4 o = oacc[mi][nt];
#pragma unroll
      for (int r = 0; r < 4; r++) {
        int wrow = wv * 32 + mi * 16 + (lane >> 4) * 4 + r;
        if (wrow < 225)
          op[(obase + wrow) * 512 + head * 128 + nt * 16 + mrow] = f2b(definan(o[r] * ri[r]));
      }
    }
  }
}

// ---------- launch ----------
extern "C" void kernel_launch(void* const* d_in, const int* in_sizes, int n_in,
                              void* d_out, int out_size, void* d_ws, size_t ws_size,
                              hipStream_t stream) {
  const float* x  = (const float*)d_in[0];
  const float* xp = (const float*)d_in[1];
  const float* qw = (const float*)d_in[2];
  const float* qb = (const float*)d_in[3];
  const float* pw = (const float*)d_in[4];
  const float* pb = (const float*)d_in[5];

  char* ws = (char*)d_ws;
  unsigned short* arena = (unsigned short*)ws;           // 18,008,064 el = 36,016,128 B
  unsigned short* x_b  = arena;                          // 16,588,800 el
  unsigned short* xp_b = arena + 16588800;
  unsigned short* qw_b = arena + 16957440;
  unsigned short* qb_b = arena + 17743872;
  unsigned short* pw_b = arena + 17745408;
  unsigned short* pb_b = arena + 18007552;
  unsigned short* qkv_ws = (unsigned short*)(ws + 36016128);   // 99,532,800 B
  unsigned short* kp     = (unsigned short*)(ws + 135549056);  // 1,638,400 B
  unsigned short* vp     = kp + 819200;                        // 1,638,400 B
  unsigned short* out_pre = x_b;  // overlay: x dead after gemm1

  // fp32 inputs -> bf16 arena
  convert_inputs<<<8793, 256, 0, stream>>>(x, xp, qw, qb, pw, pb, arena);

  // zero the padded pooled k/v (supplies unfold's zero padding)
  hipMemsetAsync(kp, 0, 2 * 819200 * sizeof(unsigned short), stream);

  // QKV projection for x tokens -> bf16
  dim3 g1(254, 12);
  gemm_bt<<<g1, 256, 0, stream>>>(x_b, qw_b, qb_b, qkv_ws, 32400, 512, 512, 512, 1536, 0);

  // pooled k/v
  pooled_qkv<<<2880, 256, 0, stream>>>(xp_b, qw_b, qb_b, kp, vp);

  // fused attention -> bf16 pre-projection activations
  dim3 g3(144, 4);
  attn_win<<<g3, 512, 0, stream>>>(qkv_ws, kp, vp, out_pre);

  // output projection -> FLOAT32 d_out (reference output dtype)
  dim3 g4(254, 4);
  gemm_bt<<<g4, 256, 0, stream>>>(out_pre, pw_b, pb_b, d_out, 32400, 512, 512, 512, 512, 1);
}